// Round 7
// baseline (900.794 us; speedup 1.0000x reference)
//
#include <hip/hip_runtime.h>
#include <math.h>

#define IN_DIM 256
#define OUT_DIM 64
#define BROWS 256            // dst rows per bucket
#define EPB 16               // edges per thread in pass-1 multisplit
#define P1_EDGES (256 * EPB) // 4096 edges per block
#define GEMM_BLOCKS 512      // 2 blocks/CU

// broadcast lane l's value to all lanes via v_readlane (l must be wave-uniform
// -- here always a literal after full unroll), result lands in an SGPR and is
// consumed as the scalar operand of v_fmac.
__device__ __forceinline__ float bcast(float v, int l) {
    return __uint_as_float(__builtin_amdgcn_readlane(__float_as_uint(v), l));
}

// ---------------------------------------------------------------------------
// K1: out-degree histogram only (in-degree comes free from CSR row extents).
// ---------------------------------------------------------------------------
__global__ void deg_kernel(const int* __restrict__ src,
                           int* __restrict__ out_deg, int n_edges) {
    int e = blockIdx.x * blockDim.x + threadIdx.x;
    if (e < n_edges) atomicAdd(&out_deg[src[e]], 1);
}

// ---------------------------------------------------------------------------
// K2: bucket histogram over dst>>8. LDS-privatized.
// ---------------------------------------------------------------------------
__global__ void __launch_bounds__(256) hist_kernel(
        const int* __restrict__ dst, int* __restrict__ bucket_hist,
        int n_edges, int nb) {
    __shared__ int lh[512];
    for (int i = threadIdx.x; i < nb; i += 256) lh[i] = 0;
    __syncthreads();
    const int base = blockIdx.x * P1_EDGES;
    #pragma unroll
    for (int i = 0; i < EPB; ++i) {
        int e = base + i * 256 + threadIdx.x;
        if (e < n_edges) atomicAdd(&lh[dst[e] >> 8], 1);
    }
    __syncthreads();
    for (int i = threadIdx.x; i < nb; i += 256)
        if (lh[i]) atomicAdd(&bucket_hist[i], lh[i]);
}

// ---------------------------------------------------------------------------
// K3: exclusive scan of bucket counts (tiny; nb ~ 391). Also writes
// row_start[n_nodes] = n_edges.
// ---------------------------------------------------------------------------
__global__ void bucket_scan_kernel(const int* __restrict__ hist,
                                   int* __restrict__ base, int* __restrict__ cursor,
                                   int* __restrict__ row_start,
                                   int nb, int n_nodes) {
    if (threadIdx.x == 0 && blockIdx.x == 0) {
        int acc = 0;
        for (int i = 0; i < nb; ++i) {
            base[i] = acc;
            cursor[i] = acc;
            acc += hist[i];
        }
        base[nb] = acc;
        row_start[n_nodes] = acc;
    }
}

// ---------------------------------------------------------------------------
// K4: pass-1 multisplit. Block-local LDS counts -> one global atomic
// reservation per (block,bucket) -> packed (src<<8 | dst&255) written into
// per-bucket segments (~40B each; no 64B-line-per-4B write amplification).
// ---------------------------------------------------------------------------
__global__ void __launch_bounds__(256) scatter_pairs_kernel(
        const int* __restrict__ src, const int* __restrict__ dst,
        int* __restrict__ cursor, unsigned* __restrict__ pairs,
        int n_edges, int nb) {
    __shared__ int lh[512];     // per-bucket local count, then local cursor
    __shared__ int lbase[512];  // per-bucket reserved global base
    for (int i = threadIdx.x; i < nb; i += 256) lh[i] = 0;
    __syncthreads();

    const int base = blockIdx.x * P1_EDGES;
    int s[EPB], d[EPB];
    #pragma unroll
    for (int i = 0; i < EPB; ++i) {
        int e = base + i * 256 + threadIdx.x;
        if (e < n_edges) {
            s[i] = src[e];
            d[i] = dst[e];
            atomicAdd(&lh[d[i] >> 8], 1);
        } else {
            s[i] = -1; d[i] = 0;
        }
    }
    __syncthreads();
    for (int i = threadIdx.x; i < nb; i += 256) {
        int c = lh[i];
        lbase[i] = c ? atomicAdd(&cursor[i], c) : 0;
        lh[i] = 0;  // reuse as local cursor
    }
    __syncthreads();
    #pragma unroll
    for (int i = 0; i < EPB; ++i) {
        if (s[i] >= 0) {
            int bkt = d[i] >> 8;
            int pos = lbase[bkt] + atomicAdd(&lh[bkt], 1);
            pairs[pos] = ((unsigned)s[i] << 8) | (unsigned)(d[i] & 255);
        }
    }
}

// ---------------------------------------------------------------------------
// K5: bucket -> exact CSR. One block per bucket: LDS histogram of dst&255,
// block scan -> row_start, then scatter src into csr_src. All scatter writes
// land in this bucket's ~32 KB contiguous window -> L2 absorbs them.
// ---------------------------------------------------------------------------
__global__ void __launch_bounds__(256) bucket2csr_kernel(
        const unsigned* __restrict__ pairs, const int* __restrict__ bucket_base,
        int* __restrict__ row_start, int* __restrict__ csr_src, int n_nodes) {
    __shared__ int cnt[BROWS];
    __shared__ int scan[BROWS];
    const int b = blockIdx.x;
    const int beg = bucket_base[b];
    const int end = bucket_base[b + 1];
    const int rowBase = b * BROWS;

    cnt[threadIdx.x] = 0;
    __syncthreads();
    for (int i = beg + threadIdx.x; i < end; i += 256)
        atomicAdd(&cnt[pairs[i] & 255u], 1);
    __syncthreads();

    // inclusive block scan (Hillis-Steele over 256 elements)
    int v = cnt[threadIdx.x];
    scan[threadIdx.x] = v;
    __syncthreads();
    #pragma unroll
    for (int dstep = 1; dstep < 256; dstep <<= 1) {
        int t = (threadIdx.x >= dstep) ? scan[threadIdx.x - dstep] : 0;
        __syncthreads();
        scan[threadIdx.x] += t;
        __syncthreads();
    }
    const int excl = scan[threadIdx.x] - v;

    const int row = rowBase + threadIdx.x;
    if (row < n_nodes) row_start[row] = beg + excl;
    cnt[threadIdx.x] = beg + excl;  // reuse as cursor
    __syncthreads();

    for (int i = beg + threadIdx.x; i < end; i += 256) {
        unsigned p = pairs[i];
        int pos = atomicAdd(&cnt[p & 255u], 1);
        csr_src[pos] = (int)(p >> 8);
    }
}

// ---------------------------------------------------------------------------
// K6: m[row] = (h[row] @ W) * rsqrt(max(out_deg,1)).
// Persistent; W in LDS once per block. Per 4-row tile: lane l loads
// h[row][4l..4l+3] (fully coalesced dwordx4), then the k-loop is FULLY
// unrolled so __builtin_amdgcn_readlane broadcasts h values through SGPRs
// directly into v_fmac against W[k][lane] from LDS. VMEM instr count per row:
// 1 (vs 64 broadcast loads before).
// ---------------------------------------------------------------------------
__global__ void __launch_bounds__(256) gemm_kernel(
        const float* __restrict__ h, const float* __restrict__ W,
        const int* __restrict__ out_deg, float* __restrict__ m, int n_nodes) {
    __shared__ float Wl[IN_DIM * OUT_DIM];  // 64 KB
    {
        const float4* W4 = (const float4*)W;
        float4* Wl4 = (float4*)Wl;
        #pragma unroll
        for (int i = 0; i < (IN_DIM * OUT_DIM / 4) / 256; ++i)
            Wl4[threadIdx.x + i * 256] = W4[threadIdx.x + i * 256];
    }
    __syncthreads();

    const int lane = threadIdx.x & 63;
    const int waveId = (blockIdx.x << 2) | (threadIdx.x >> 6);
    const int nWaves = gridDim.x << 2;

    const int nTiles = (n_nodes + 3) >> 2;  // 4-row tiles
    for (int tile = waveId; tile < nTiles; tile += nWaves) {
        const int rowBase = tile << 2;
        const int nr = min(4, n_nodes - rowBase);

        // coalesced: lane l holds h[rowBase+r][4l .. 4l+3]
        const float4* __restrict__ hp = (const float4*)(h + (size_t)rowBase * IN_DIM);
        float4 hreg[4];
        #pragma unroll
        for (int r = 0; r < 4; ++r)
            hreg[r] = (r < nr) ? hp[r * (IN_DIM / 4) + lane]
                               : make_float4(0.f, 0.f, 0.f, 0.f);

        float acc[4] = {0.f, 0.f, 0.f, 0.f};

        #pragma unroll
        for (int k4 = 0; k4 < IN_DIM / 4; ++k4) {
            float w0 = Wl[(k4 * 4 + 0) * OUT_DIM + lane];
            float w1 = Wl[(k4 * 4 + 1) * OUT_DIM + lane];
            float w2 = Wl[(k4 * 4 + 2) * OUT_DIM + lane];
            float w3 = Wl[(k4 * 4 + 3) * OUT_DIM + lane];
            #pragma unroll
            for (int r = 0; r < 4; ++r) {
                acc[r] += bcast(hreg[r].x, k4) * w0;
                acc[r] += bcast(hreg[r].y, k4) * w1;
                acc[r] += bcast(hreg[r].z, k4) * w2;
                acc[r] += bcast(hreg[r].w, k4) * w3;
            }
        }

        #pragma unroll
        for (int r = 0; r < 4; ++r) {
            if (r < nr) {
                float nrm = rsqrtf(fmaxf((float)out_deg[rowBase + r], 1.0f));
                m[(size_t)(rowBase + r) * OUT_DIM + lane] = acc[r] * nrm;
            }
        }
    }
}

// ---------------------------------------------------------------------------
// K7: CSR gather per dst row + fused norm_dst + bias + log_softmax.
// One wave per row; 8 gathers in flight; in-degree = row extent.
// ---------------------------------------------------------------------------
__global__ void __launch_bounds__(256) gather_kernel(
        const int* __restrict__ row_start, const int* __restrict__ csr_src,
        const float* __restrict__ m, const float* __restrict__ b,
        float* __restrict__ out, int n_nodes) {
    const int wave = threadIdx.x >> 6;
    const int lane = threadIdx.x & 63;
    const int row = blockIdx.x * 4 + wave;
    if (row >= n_nodes) return;

    const int beg = row_start[row];
    const int end = row_start[row + 1];

    float acc = 0.f;
    int i = beg;
    for (; i + 8 <= end; i += 8) {
        int s0 = csr_src[i + 0];
        int s1 = csr_src[i + 1];
        int s2 = csr_src[i + 2];
        int s3 = csr_src[i + 3];
        int s4 = csr_src[i + 4];
        int s5 = csr_src[i + 5];
        int s6 = csr_src[i + 6];
        int s7 = csr_src[i + 7];
        float v0 = m[(size_t)s0 * OUT_DIM + lane];
        float v1 = m[(size_t)s1 * OUT_DIM + lane];
        float v2 = m[(size_t)s2 * OUT_DIM + lane];
        float v3 = m[(size_t)s3 * OUT_DIM + lane];
        float v4 = m[(size_t)s4 * OUT_DIM + lane];
        float v5 = m[(size_t)s5 * OUT_DIM + lane];
        float v6 = m[(size_t)s6 * OUT_DIM + lane];
        float v7 = m[(size_t)s7 * OUT_DIM + lane];
        acc += v0 + v1 + v2 + v3 + v4 + v5 + v6 + v7;
    }
    for (; i < end; ++i) acc += m[(size_t)csr_src[i] * OUT_DIM + lane];

    float nd = rsqrtf(fmaxf((float)(end - beg), 1.0f));
    float x = acc * nd + b[lane];

    float mx = x;
    #pragma unroll
    for (int o = 32; o > 0; o >>= 1) mx = fmaxf(mx, __shfl_xor(mx, o, 64));
    float ex = expf(x - mx);
    float s = ex;
    #pragma unroll
    for (int o = 32; o > 0; o >>= 1) s += __shfl_xor(s, o, 64);
    out[(size_t)row * OUT_DIM + lane] = x - mx - logf(s);
}

// ---------------------------------------------------------------------------
static inline size_t align16(size_t x) { return (x + 15) & ~(size_t)15; }

extern "C" void kernel_launch(void* const* d_in, const int* in_sizes, int n_in,
                              void* d_out, int out_size, void* d_ws, size_t ws_size,
                              hipStream_t stream) {
    const float* h = (const float*)d_in[0];
    const float* W = (const float*)d_in[1];
    const float* b = (const float*)d_in[2];
    const int* edges = (const int*)d_in[3];

    const int out_dim = in_sizes[2];            // 64
    const int in_dim  = in_sizes[1] / out_dim;  // 256
    const int n_nodes = in_sizes[0] / in_dim;   // 100000
    const int n_edges = in_sizes[3] / 2;        // 3200000

    const int* src = edges;
    const int* dst = edges + n_edges;

    float* out = (float*)d_out;

    const int nb = (n_nodes + BROWS - 1) / BROWS;  // 391 buckets

    // workspace carve-up
    char* ws = (char*)d_ws;
    size_t off = 0;
    int* out_deg       = (int*)(ws + off); off = align16(off + (size_t)n_nodes * 4);
    int* row_start     = (int*)(ws + off); off = align16(off + (size_t)(n_nodes + 1) * 4);
    int* bucket_hist   = (int*)(ws + off); off = align16(off + (size_t)nb * 4);
    int* bucket_base   = (int*)(ws + off); off = align16(off + (size_t)(nb + 1) * 4);
    int* bucket_cursor = (int*)(ws + off); off = align16(off + (size_t)nb * 4);
    float* m           = (float*)(ws + off); off = align16(off + (size_t)n_nodes * OUT_DIM * 4);
    unsigned* pairs    = (unsigned*)(ws + off); off = align16(off + (size_t)n_edges * 4);
    int* csr_src       = (int*)(ws + off); off = align16(off + (size_t)n_edges * 4);

    (void)hipMemsetAsync(out_deg, 0, (size_t)n_nodes * sizeof(int), stream);
    (void)hipMemsetAsync(bucket_hist, 0, (size_t)nb * sizeof(int), stream);

    const int p1_blocks = (n_edges + P1_EDGES - 1) / P1_EDGES;

    deg_kernel<<<(n_edges + 255) / 256, 256, 0, stream>>>(src, out_deg, n_edges);

    hist_kernel<<<p1_blocks, 256, 0, stream>>>(dst, bucket_hist, n_edges, nb);
    bucket_scan_kernel<<<1, 64, 0, stream>>>(bucket_hist, bucket_base, bucket_cursor,
                                             row_start, nb, n_nodes);
    scatter_pairs_kernel<<<p1_blocks, 256, 0, stream>>>(src, dst, bucket_cursor, pairs, n_edges, nb);
    bucket2csr_kernel<<<nb, 256, 0, stream>>>(pairs, bucket_base, row_start, csr_src, n_nodes);

    gemm_kernel<<<GEMM_BLOCKS, 256, 0, stream>>>(h, W, out_deg, m, n_nodes);

    gather_kernel<<<(n_nodes + 3) / 4, 256, 0, stream>>>(row_start, csr_src, m, b, out, n_nodes);
}

// Round 8
// 585.539 us; speedup vs baseline: 1.5384x; 1.5384x over previous
//
#include <hip/hip_runtime.h>
#include <math.h>

#define IN_DIM 256
#define OUT_DIM 64
#define BROWS 256            // dst rows per bucket
#define EPB 16               // edges per thread in pass-1 multisplit
#define P1_EDGES (256 * EPB) // 4096 edges per block
#define BM 128               // gemm rows per block
#define KC 32                // gemm k-chunk
#define HS_LD 33             // padded leading dim of h tile in LDS

// ---------------------------------------------------------------------------
// K1: fused out-degree histogram + dst-bucket histogram. One edge-list pass.
// ---------------------------------------------------------------------------
__global__ void __launch_bounds__(256) hist_kernel(
        const int* __restrict__ src, const int* __restrict__ dst,
        int* __restrict__ out_deg, int* __restrict__ bucket_hist,
        int n_edges, int nb) {
    __shared__ int lh[512];
    for (int i = threadIdx.x; i < nb; i += 256) lh[i] = 0;
    __syncthreads();
    const int base = blockIdx.x * P1_EDGES;
    #pragma unroll
    for (int i = 0; i < EPB; ++i) {
        int e = base + i * 256 + threadIdx.x;
        if (e < n_edges) {
            atomicAdd(&lh[dst[e] >> 8], 1);
            atomicAdd(&out_deg[src[e]], 1);
        }
    }
    __syncthreads();
    for (int i = threadIdx.x; i < nb; i += 256)
        if (lh[i]) atomicAdd(&bucket_hist[i], lh[i]);
}

// ---------------------------------------------------------------------------
// K2: exclusive scan of bucket counts (tiny; nb ~ 391). Also writes
// row_start[n_nodes] = n_edges.
// ---------------------------------------------------------------------------
__global__ void bucket_scan_kernel(const int* __restrict__ hist,
                                   int* __restrict__ base, int* __restrict__ cursor,
                                   int* __restrict__ row_start,
                                   int nb, int n_nodes) {
    if (threadIdx.x == 0 && blockIdx.x == 0) {
        int acc = 0;
        for (int i = 0; i < nb; ++i) {
            base[i] = acc;
            cursor[i] = acc;
            acc += hist[i];
        }
        base[nb] = acc;
        row_start[n_nodes] = acc;
    }
}

// ---------------------------------------------------------------------------
// K3: pass-1 multisplit. Block-local LDS counts -> one global atomic
// reservation per (block,bucket) -> packed (src<<8 | dst&255) written into
// per-bucket segments (~40B each; no 64B-line-per-4B write amplification).
// ---------------------------------------------------------------------------
__global__ void __launch_bounds__(256) scatter_pairs_kernel(
        const int* __restrict__ src, const int* __restrict__ dst,
        int* __restrict__ cursor, unsigned* __restrict__ pairs,
        int n_edges, int nb) {
    __shared__ int lh[512];     // per-bucket local count, then local cursor
    __shared__ int lbase[512];  // per-bucket reserved global base
    for (int i = threadIdx.x; i < nb; i += 256) lh[i] = 0;
    __syncthreads();

    const int base = blockIdx.x * P1_EDGES;
    int s[EPB], d[EPB];
    #pragma unroll
    for (int i = 0; i < EPB; ++i) {
        int e = base + i * 256 + threadIdx.x;
        if (e < n_edges) {
            s[i] = src[e];
            d[i] = dst[e];
            atomicAdd(&lh[d[i] >> 8], 1);
        } else {
            s[i] = -1; d[i] = 0;
        }
    }
    __syncthreads();
    for (int i = threadIdx.x; i < nb; i += 256) {
        int c = lh[i];
        lbase[i] = c ? atomicAdd(&cursor[i], c) : 0;
        lh[i] = 0;  // reuse as local cursor
    }
    __syncthreads();
    #pragma unroll
    for (int i = 0; i < EPB; ++i) {
        if (s[i] >= 0) {
            int bkt = d[i] >> 8;
            int pos = lbase[bkt] + atomicAdd(&lh[bkt], 1);
            pairs[pos] = ((unsigned)s[i] << 8) | (unsigned)(d[i] & 255);
        }
    }
}

// ---------------------------------------------------------------------------
// K4: bucket -> exact CSR. One block per bucket: LDS histogram of dst&255,
// block scan -> row_start, then scatter src into csr_src. All scatter writes
// land in this bucket's ~32 KB contiguous window -> L2 absorbs them.
// ---------------------------------------------------------------------------
__global__ void __launch_bounds__(256) bucket2csr_kernel(
        const unsigned* __restrict__ pairs, const int* __restrict__ bucket_base,
        int* __restrict__ row_start, int* __restrict__ csr_src, int n_nodes) {
    __shared__ int cnt[BROWS];
    __shared__ int scan[BROWS];
    const int b = blockIdx.x;
    const int beg = bucket_base[b];
    const int end = bucket_base[b + 1];
    const int rowBase = b * BROWS;

    cnt[threadIdx.x] = 0;
    __syncthreads();
    for (int i = beg + threadIdx.x; i < end; i += 256)
        atomicAdd(&cnt[pairs[i] & 255u], 1);
    __syncthreads();

    // inclusive block scan (Hillis-Steele over 256 elements)
    int v = cnt[threadIdx.x];
    scan[threadIdx.x] = v;
    __syncthreads();
    #pragma unroll
    for (int dstep = 1; dstep < 256; dstep <<= 1) {
        int t = (threadIdx.x >= dstep) ? scan[threadIdx.x - dstep] : 0;
        __syncthreads();
        scan[threadIdx.x] += t;
        __syncthreads();
    }
    const int excl = scan[threadIdx.x] - v;

    const int row = rowBase + threadIdx.x;
    if (row < n_nodes) row_start[row] = beg + excl;
    cnt[threadIdx.x] = beg + excl;  // reuse as cursor
    __syncthreads();

    for (int i = beg + threadIdx.x; i < end; i += 256) {
        unsigned p = pairs[i];
        int pos = atomicAdd(&cnt[p & 255u], 1);
        csr_src[pos] = (int)(p >> 8);
    }
}

// ---------------------------------------------------------------------------
// K5: register-tiled GEMM. m[row] = (h[row] @ W) * rsqrt(max(out_deg,1)).
// Block = 256 threads, tile = 128 rows x 64 cols. Thread (g=t>>4, c=t&15)
// owns rows g*8..g*8+7 x cols c*4..c*4+3 -> acc[8][4] in registers.
// k in 8 chunks of 32: stage h-tile (128x33 padded, 16.9 KB) + W-chunk
// (32x64, 8 KB) in LDS, then per k-step: 8x ds_read_b32 (a, 4 distinct
// rows/wave, conflict-free via pad 33) + 1x ds_read_b128 (b, broadcast x4)
// feed 32 FMAs. ~25 KB LDS -> ~6 blocks/CU.
// ---------------------------------------------------------------------------
__global__ void __launch_bounds__(256) gemm_kernel(
        const float* __restrict__ h, const float* __restrict__ W,
        const int* __restrict__ out_deg, float* __restrict__ m, int n_nodes) {
    __shared__ float hs[BM * HS_LD];       // 16.9 KB
    __shared__ float Ws[KC * OUT_DIM];     // 8 KB

    const int t = threadIdx.x;
    const int c = t & 15;   // col group (4 cols)
    const int g = t >> 4;   // row group (8 rows)
    const int rowBase = blockIdx.x * BM;

    float acc[8][4];
    #pragma unroll
    for (int i = 0; i < 8; ++i)
        #pragma unroll
        for (int j = 0; j < 4; ++j) acc[i][j] = 0.f;

    for (int kc = 0; kc < IN_DIM / KC; ++kc) {
        __syncthreads();  // protect LDS from previous chunk's readers
        // stage h chunk: 1024 float4 loads (coalesced), scalar LDS writes
        #pragma unroll
        for (int i = 0; i < 4; ++i) {
            int idx = t + 256 * i;      // 0..1023
            int row = idx >> 3;         // 0..127
            int seg = idx & 7;          // k offset = seg*4
            int grow = rowBase + row;
            float4 v = make_float4(0.f, 0.f, 0.f, 0.f);
            if (grow < n_nodes)
                v = *(const float4*)(h + (size_t)grow * IN_DIM + kc * KC + seg * 4);
            float* dp = &hs[row * HS_LD + seg * 4];
            dp[0] = v.x; dp[1] = v.y; dp[2] = v.z; dp[3] = v.w;
        }
        // stage W chunk: 512 float4 -> 2 per thread (aligned b128)
        {
            const float4* Wg = (const float4*)(W + kc * KC * OUT_DIM);
            float4* Wl = (float4*)Ws;
            Wl[t] = Wg[t];
            Wl[t + 256] = Wg[t + 256];
        }
        __syncthreads();

        #pragma unroll 4
        for (int kk = 0; kk < KC; ++kk) {
            float4 bv = *(const float4*)&Ws[kk * OUT_DIM + c * 4];
            #pragma unroll
            for (int i = 0; i < 8; ++i) {
                float a = hs[(g * 8 + i) * HS_LD + kk];
                acc[i][0] += a * bv.x;
                acc[i][1] += a * bv.y;
                acc[i][2] += a * bv.z;
                acc[i][3] += a * bv.w;
            }
        }
    }

    #pragma unroll
    for (int i = 0; i < 8; ++i) {
        int row = rowBase + g * 8 + i;
        if (row < n_nodes) {
            float nr = rsqrtf(fmaxf((float)out_deg[row], 1.0f));
            float4 o = make_float4(acc[i][0] * nr, acc[i][1] * nr,
                                   acc[i][2] * nr, acc[i][3] * nr);
            *(float4*)(m + (size_t)row * OUT_DIM + c * 4) = o;
        }
    }
}

// ---------------------------------------------------------------------------
// K6: CSR gather per dst row + fused norm_dst + bias + log_softmax.
// One wave per row; 8 gathers in flight; in-degree = row extent.
// ---------------------------------------------------------------------------
__global__ void __launch_bounds__(256) gather_kernel(
        const int* __restrict__ row_start, const int* __restrict__ csr_src,
        const float* __restrict__ m, const float* __restrict__ b,
        float* __restrict__ out, int n_nodes) {
    const int wave = threadIdx.x >> 6;
    const int lane = threadIdx.x & 63;
    const int row = blockIdx.x * 4 + wave;
    if (row >= n_nodes) return;

    const int beg = row_start[row];
    const int end = row_start[row + 1];

    float acc = 0.f;
    int i = beg;
    for (; i + 8 <= end; i += 8) {
        int s0 = csr_src[i + 0];
        int s1 = csr_src[i + 1];
        int s2 = csr_src[i + 2];
        int s3 = csr_src[i + 3];
        int s4 = csr_src[i + 4];
        int s5 = csr_src[i + 5];
        int s6 = csr_src[i + 6];
        int s7 = csr_src[i + 7];
        float v0 = m[(size_t)s0 * OUT_DIM + lane];
        float v1 = m[(size_t)s1 * OUT_DIM + lane];
        float v2 = m[(size_t)s2 * OUT_DIM + lane];
        float v3 = m[(size_t)s3 * OUT_DIM + lane];
        float v4 = m[(size_t)s4 * OUT_DIM + lane];
        float v5 = m[(size_t)s5 * OUT_DIM + lane];
        float v6 = m[(size_t)s6 * OUT_DIM + lane];
        float v7 = m[(size_t)s7 * OUT_DIM + lane];
        acc += v0 + v1 + v2 + v3 + v4 + v5 + v6 + v7;
    }
    for (; i < end; ++i) acc += m[(size_t)csr_src[i] * OUT_DIM + lane];

    float nd = rsqrtf(fmaxf((float)(end - beg), 1.0f));
    float x = acc * nd + b[lane];

    float mx = x;
    #pragma unroll
    for (int o = 32; o > 0; o >>= 1) mx = fmaxf(mx, __shfl_xor(mx, o, 64));
    float ex = expf(x - mx);
    float s = ex;
    #pragma unroll
    for (int o = 32; o > 0; o >>= 1) s += __shfl_xor(s, o, 64);
    out[(size_t)row * OUT_DIM + lane] = x - mx - logf(s);
}

// ---------------------------------------------------------------------------
static inline size_t align16(size_t x) { return (x + 15) & ~(size_t)15; }

extern "C" void kernel_launch(void* const* d_in, const int* in_sizes, int n_in,
                              void* d_out, int out_size, void* d_ws, size_t ws_size,
                              hipStream_t stream) {
    const float* h = (const float*)d_in[0];
    const float* W = (const float*)d_in[1];
    const float* b = (const float*)d_in[2];
    const int* edges = (const int*)d_in[3];

    const int out_dim = in_sizes[2];            // 64
    const int in_dim  = in_sizes[1] / out_dim;  // 256
    const int n_nodes = in_sizes[0] / in_dim;   // 100000
    const int n_edges = in_sizes[3] / 2;        // 3200000

    const int* src = edges;
    const int* dst = edges + n_edges;

    float* out = (float*)d_out;

    const int nb = (n_nodes + BROWS - 1) / BROWS;  // 391 buckets

    // workspace carve-up
    char* ws = (char*)d_ws;
    size_t off = 0;
    int* out_deg       = (int*)(ws + off); off = align16(off + (size_t)n_nodes * 4);
    int* row_start     = (int*)(ws + off); off = align16(off + (size_t)(n_nodes + 1) * 4);
    int* bucket_hist   = (int*)(ws + off); off = align16(off + (size_t)nb * 4);
    int* bucket_base   = (int*)(ws + off); off = align16(off + (size_t)(nb + 1) * 4);
    int* bucket_cursor = (int*)(ws + off); off = align16(off + (size_t)nb * 4);
    float* m           = (float*)(ws + off); off = align16(off + (size_t)n_nodes * OUT_DIM * 4);
    unsigned* pairs    = (unsigned*)(ws + off); off = align16(off + (size_t)n_edges * 4);
    int* csr_src       = (int*)(ws + off); off = align16(off + (size_t)n_edges * 4);

    (void)hipMemsetAsync(out_deg, 0, (size_t)n_nodes * sizeof(int), stream);
    (void)hipMemsetAsync(bucket_hist, 0, (size_t)nb * sizeof(int), stream);

    const int p1_blocks = (n_edges + P1_EDGES - 1) / P1_EDGES;

    hist_kernel<<<p1_blocks, 256, 0, stream>>>(src, dst, out_deg, bucket_hist, n_edges, nb);
    bucket_scan_kernel<<<1, 64, 0, stream>>>(bucket_hist, bucket_base, bucket_cursor,
                                             row_start, nb, n_nodes);
    scatter_pairs_kernel<<<p1_blocks, 256, 0, stream>>>(src, dst, bucket_cursor, pairs, n_edges, nb);
    bucket2csr_kernel<<<nb, 256, 0, stream>>>(pairs, bucket_base, row_start, csr_src, n_nodes);

    gemm_kernel<<<(n_nodes + BM - 1) / BM, 256, 0, stream>>>(h, W, out_deg, m, n_nodes);

    gather_kernel<<<(n_nodes + 3) / 4, 256, 0, stream>>>(row_start, csr_src, m, b, out, n_nodes);
}

// Round 9
// 517.668 us; speedup vs baseline: 1.7401x; 1.1311x over previous
//
#include <hip/hip_runtime.h>
#include <math.h>

#define IN_DIM 256
#define OUT_DIM 64
#define BROWS 256             // nodes per bucket
#define HIST_EDGES 8192       // edges per hist block
#define SC_THREADS 512
#define SC_EPB 16
#define SC_EDGES (SC_THREADS * SC_EPB)  // 8192 edges per scatter block
#define BM 128                // gemm rows per block
#define KC 32                 // gemm k-chunk
#define HS_LD 33              // padded leading dim of h tile in LDS

// ---------------------------------------------------------------------------
// K1: dual bucket histogram (dst>>8 and src>>8), LDS-privatized, one edge
// pass, NO per-node atomics. hist layout: [0..nb) = dst buckets,
// [nb..2nb) = src buckets.
// ---------------------------------------------------------------------------
__global__ void __launch_bounds__(256) hist_kernel(
        const int* __restrict__ src, const int* __restrict__ dst,
        int* __restrict__ hist2, int n_edges, int nb) {
    __shared__ int lhd[512];
    __shared__ int lhs[512];
    for (int i = threadIdx.x; i < nb; i += 256) { lhd[i] = 0; lhs[i] = 0; }
    __syncthreads();
    const int base = blockIdx.x * HIST_EDGES;
    for (int i = threadIdx.x; i < HIST_EDGES; i += 256) {
        int e = base + i;
        if (e < n_edges) {
            atomicAdd(&lhd[dst[e] >> 8], 1);
            atomicAdd(&lhs[src[e] >> 8], 1);
        }
    }
    __syncthreads();
    for (int i = threadIdx.x; i < nb; i += 256) {
        if (lhd[i]) atomicAdd(&hist2[i], lhd[i]);
        if (lhs[i]) atomicAdd(&hist2[nb + i], lhs[i]);
    }
}

// ---------------------------------------------------------------------------
// K2: exclusive scans of both bucket histograms (tiny; nb ~ 391).
// ---------------------------------------------------------------------------
__global__ void bucket_scan_kernel(const int* __restrict__ hist2,
                                   int* __restrict__ dbase, int* __restrict__ dcursor,
                                   int* __restrict__ sbase, int* __restrict__ scursor,
                                   int* __restrict__ row_start,
                                   int nb, int n_nodes) {
    if (threadIdx.x == 0 && blockIdx.x == 0) {
        int acc = 0;
        for (int i = 0; i < nb; ++i) {
            dbase[i] = acc; dcursor[i] = acc;
            acc += hist2[i];
        }
        dbase[nb] = acc;
        row_start[n_nodes] = acc;
        acc = 0;
        for (int i = 0; i < nb; ++i) {
            sbase[i] = acc; scursor[i] = acc;
            acc += hist2[nb + i];
        }
        sbase[nb] = acc;
    }
}

// ---------------------------------------------------------------------------
// K3: dual multisplit, one edge pass. (a) packed (src<<8 | dst&255) into
// dst-bucket segments; (b) byte (src&255) into src-bucket segments. Segment
// reservation = one global atomic per (block,bucket) per split.
// ---------------------------------------------------------------------------
__global__ void __launch_bounds__(SC_THREADS) scatter_pairs_kernel(
        const int* __restrict__ src, const int* __restrict__ dst,
        int* __restrict__ dcursor, int* __restrict__ scursor,
        unsigned* __restrict__ pairs, unsigned char* __restrict__ sbytes,
        int n_edges, int nb) {
    __shared__ int lhd[512];    // dst-bucket count, then local cursor
    __shared__ int lbd[512];    // dst-bucket reserved global base
    __shared__ int lhs[512];    // src-bucket count, then local cursor
    __shared__ int lbs[512];    // src-bucket reserved global base
    const int t = threadIdx.x;
    for (int i = t; i < nb; i += SC_THREADS) { lhd[i] = 0; lhs[i] = 0; }
    __syncthreads();

    const int base = blockIdx.x * SC_EDGES;
    int s[SC_EPB], d[SC_EPB];
    #pragma unroll
    for (int i = 0; i < SC_EPB; ++i) {
        int e = base + i * SC_THREADS + t;
        if (e < n_edges) {
            s[i] = src[e];
            d[i] = dst[e];
            atomicAdd(&lhd[d[i] >> 8], 1);
            atomicAdd(&lhs[s[i] >> 8], 1);
        } else {
            s[i] = -1; d[i] = 0;
        }
    }
    __syncthreads();
    for (int i = t; i < nb; i += SC_THREADS) {
        int c = lhd[i];
        lbd[i] = c ? atomicAdd(&dcursor[i], c) : 0;
        lhd[i] = 0;
        c = lhs[i];
        lbs[i] = c ? atomicAdd(&scursor[i], c) : 0;
        lhs[i] = 0;
    }
    __syncthreads();
    #pragma unroll
    for (int i = 0; i < SC_EPB; ++i) {
        if (s[i] >= 0) {
            int bkt = d[i] >> 8;
            int pos = lbd[bkt] + atomicAdd(&lhd[bkt], 1);
            pairs[pos] = ((unsigned)s[i] << 8) | (unsigned)(d[i] & 255);
            int sb = s[i] >> 8;
            int spos = lbs[sb] + atomicAdd(&lhs[sb], 1);
            sbytes[spos] = (unsigned char)(s[i] & 255);
        }
    }
}

// ---------------------------------------------------------------------------
// K4: bucket -> exact CSR. One block per dst-bucket: LDS histogram of
// dst&255, block scan -> row_start, scatter src into csr_src (writes land in
// a ~32 KB window -> L2 absorbs).
// ---------------------------------------------------------------------------
__global__ void __launch_bounds__(256) bucket2csr_kernel(
        const unsigned* __restrict__ pairs, const int* __restrict__ bucket_base,
        int* __restrict__ row_start, int* __restrict__ csr_src, int n_nodes) {
    __shared__ int cnt[BROWS];
    __shared__ int scan[BROWS];
    const int b = blockIdx.x;
    const int beg = bucket_base[b];
    const int end = bucket_base[b + 1];
    const int rowBase = b * BROWS;

    cnt[threadIdx.x] = 0;
    __syncthreads();
    for (int i = beg + threadIdx.x; i < end; i += 256)
        atomicAdd(&cnt[pairs[i] & 255u], 1);
    __syncthreads();

    int v = cnt[threadIdx.x];
    scan[threadIdx.x] = v;
    __syncthreads();
    #pragma unroll
    for (int dstep = 1; dstep < 256; dstep <<= 1) {
        int tv = (threadIdx.x >= dstep) ? scan[threadIdx.x - dstep] : 0;
        __syncthreads();
        scan[threadIdx.x] += tv;
        __syncthreads();
    }
    const int excl = scan[threadIdx.x] - v;

    const int row = rowBase + threadIdx.x;
    if (row < n_nodes) row_start[row] = beg + excl;
    cnt[threadIdx.x] = beg + excl;  // reuse as cursor
    __syncthreads();

    for (int i = beg + threadIdx.x; i < end; i += 256) {
        unsigned p = pairs[i];
        int pos = atomicAdd(&cnt[p & 255u], 1);
        csr_src[pos] = (int)(p >> 8);
    }
}

// ---------------------------------------------------------------------------
// K5: out_deg from src-bucket bytes. One block per src-bucket; LDS count of
// the 256 node slots, coalesced out_deg write. No global atomics.
// ---------------------------------------------------------------------------
__global__ void __launch_bounds__(256) count_src_kernel(
        const unsigned char* __restrict__ sbytes, const int* __restrict__ sbase,
        int* __restrict__ out_deg, int n_nodes) {
    __shared__ int cnt[BROWS];
    cnt[threadIdx.x] = 0;
    __syncthreads();
    const int beg = sbase[blockIdx.x];
    const int end = sbase[blockIdx.x + 1];
    for (int i = beg + threadIdx.x; i < end; i += 256)
        atomicAdd(&cnt[sbytes[i]], 1);
    __syncthreads();
    const int row = blockIdx.x * BROWS + threadIdx.x;
    if (row < n_nodes) out_deg[row] = cnt[threadIdx.x];
}

// ---------------------------------------------------------------------------
// K6: register-tiled GEMM. m[row] = (h[row] @ W) * rsqrt(max(out_deg,1)).
// 256 threads, 128x64 tile, 8x4 acc per thread; ~25 KB LDS.
// ---------------------------------------------------------------------------
__global__ void __launch_bounds__(256) gemm_kernel(
        const float* __restrict__ h, const float* __restrict__ W,
        const int* __restrict__ out_deg, float* __restrict__ m, int n_nodes) {
    __shared__ float hs[BM * HS_LD];       // 16.9 KB
    __shared__ float Ws[KC * OUT_DIM];     // 8 KB

    const int t = threadIdx.x;
    const int c = t & 15;   // col group (4 cols)
    const int g = t >> 4;   // row group (8 rows)
    const int rowBase = blockIdx.x * BM;

    float acc[8][4];
    #pragma unroll
    for (int i = 0; i < 8; ++i)
        #pragma unroll
        for (int j = 0; j < 4; ++j) acc[i][j] = 0.f;

    for (int kc = 0; kc < IN_DIM / KC; ++kc) {
        __syncthreads();
        #pragma unroll
        for (int i = 0; i < 4; ++i) {
            int idx = t + 256 * i;
            int row = idx >> 3;
            int seg = idx & 7;
            int grow = rowBase + row;
            float4 v = make_float4(0.f, 0.f, 0.f, 0.f);
            if (grow < n_nodes)
                v = *(const float4*)(h + (size_t)grow * IN_DIM + kc * KC + seg * 4);
            float* dp = &hs[row * HS_LD + seg * 4];
            dp[0] = v.x; dp[1] = v.y; dp[2] = v.z; dp[3] = v.w;
        }
        {
            const float4* Wg = (const float4*)(W + kc * KC * OUT_DIM);
            float4* Wl = (float4*)Ws;
            Wl[t] = Wg[t];
            Wl[t + 256] = Wg[t + 256];
        }
        __syncthreads();

        #pragma unroll 4
        for (int kk = 0; kk < KC; ++kk) {
            float4 bv = *(const float4*)&Ws[kk * OUT_DIM + c * 4];
            #pragma unroll
            for (int i = 0; i < 8; ++i) {
                float a = hs[(g * 8 + i) * HS_LD + kk];
                acc[i][0] += a * bv.x;
                acc[i][1] += a * bv.y;
                acc[i][2] += a * bv.z;
                acc[i][3] += a * bv.w;
            }
        }
    }

    #pragma unroll
    for (int i = 0; i < 8; ++i) {
        int row = rowBase + g * 8 + i;
        if (row < n_nodes) {
            float nr = rsqrtf(fmaxf((float)out_deg[row], 1.0f));
            float4 o = make_float4(acc[i][0] * nr, acc[i][1] * nr,
                                   acc[i][2] * nr, acc[i][3] * nr);
            *(float4*)(m + (size_t)row * OUT_DIM + c * 4) = o;
        }
    }
}

// ---------------------------------------------------------------------------
// K7: CSR gather per dst row + fused norm_dst + bias + log_softmax.
// ---------------------------------------------------------------------------
__global__ void __launch_bounds__(256) gather_kernel(
        const int* __restrict__ row_start, const int* __restrict__ csr_src,
        const float* __restrict__ m, const float* __restrict__ b,
        float* __restrict__ out, int n_nodes) {
    const int wave = threadIdx.x >> 6;
    const int lane = threadIdx.x & 63;
    const int row = blockIdx.x * 4 + wave;
    if (row >= n_nodes) return;

    const int beg = row_start[row];
    const int end = row_start[row + 1];

    float acc = 0.f;
    int i = beg;
    for (; i + 8 <= end; i += 8) {
        int s0 = csr_src[i + 0];
        int s1 = csr_src[i + 1];
        int s2 = csr_src[i + 2];
        int s3 = csr_src[i + 3];
        int s4 = csr_src[i + 4];
        int s5 = csr_src[i + 5];
        int s6 = csr_src[i + 6];
        int s7 = csr_src[i + 7];
        float v0 = m[(size_t)s0 * OUT_DIM + lane];
        float v1 = m[(size_t)s1 * OUT_DIM + lane];
        float v2 = m[(size_t)s2 * OUT_DIM + lane];
        float v3 = m[(size_t)s3 * OUT_DIM + lane];
        float v4 = m[(size_t)s4 * OUT_DIM + lane];
        float v5 = m[(size_t)s5 * OUT_DIM + lane];
        float v6 = m[(size_t)s6 * OUT_DIM + lane];
        float v7 = m[(size_t)s7 * OUT_DIM + lane];
        acc += v0 + v1 + v2 + v3 + v4 + v5 + v6 + v7;
    }
    for (; i < end; ++i) acc += m[(size_t)csr_src[i] * OUT_DIM + lane];

    float nd = rsqrtf(fmaxf((float)(end - beg), 1.0f));
    float x = acc * nd + b[lane];

    float mx = x;
    #pragma unroll
    for (int o = 32; o > 0; o >>= 1) mx = fmaxf(mx, __shfl_xor(mx, o, 64));
    float ex = expf(x - mx);
    float s = ex;
    #pragma unroll
    for (int o = 32; o > 0; o >>= 1) s += __shfl_xor(s, o, 64);
    out[(size_t)row * OUT_DIM + lane] = x - mx - logf(s);
}

// ---------------------------------------------------------------------------
static inline size_t align16(size_t x) { return (x + 15) & ~(size_t)15; }

extern "C" void kernel_launch(void* const* d_in, const int* in_sizes, int n_in,
                              void* d_out, int out_size, void* d_ws, size_t ws_size,
                              hipStream_t stream) {
    const float* h = (const float*)d_in[0];
    const float* W = (const float*)d_in[1];
    const float* b = (const float*)d_in[2];
    const int* edges = (const int*)d_in[3];

    const int out_dim = in_sizes[2];            // 64
    const int in_dim  = in_sizes[1] / out_dim;  // 256
    const int n_nodes = in_sizes[0] / in_dim;   // 100000
    const int n_edges = in_sizes[3] / 2;        // 3200000

    const int* src = edges;
    const int* dst = edges + n_edges;

    float* out = (float*)d_out;

    const int nb = (n_nodes + BROWS - 1) / BROWS;  // 391 buckets

    // workspace carve-up
    char* ws = (char*)d_ws;
    size_t off = 0;
    int* out_deg     = (int*)(ws + off); off = align16(off + (size_t)n_nodes * 4);
    int* row_start   = (int*)(ws + off); off = align16(off + (size_t)(n_nodes + 1) * 4);
    int* hist2       = (int*)(ws + off); off = align16(off + (size_t)(2 * nb) * 4);
    int* dbase       = (int*)(ws + off); off = align16(off + (size_t)(nb + 1) * 4);
    int* dcursor     = (int*)(ws + off); off = align16(off + (size_t)nb * 4);
    int* sbase       = (int*)(ws + off); off = align16(off + (size_t)(nb + 1) * 4);
    int* scursor     = (int*)(ws + off); off = align16(off + (size_t)nb * 4);
    float* m         = (float*)(ws + off); off = align16(off + (size_t)n_nodes * OUT_DIM * 4);
    unsigned* pairs  = (unsigned*)(ws + off); off = align16(off + (size_t)n_edges * 4);
    int* csr_src     = (int*)(ws + off); off = align16(off + (size_t)n_edges * 4);
    // sbytes aliases m's storage: written by scatter, consumed by count_src,
    // both strictly before gemm writes m (serial stream ordering).
    unsigned char* sbytes = (unsigned char*)m;

    (void)hipMemsetAsync(hist2, 0, (size_t)(2 * nb) * sizeof(int), stream);

    const int hist_blocks = (n_edges + HIST_EDGES - 1) / HIST_EDGES;
    const int sc_blocks   = (n_edges + SC_EDGES - 1) / SC_EDGES;

    hist_kernel<<<hist_blocks, 256, 0, stream>>>(src, dst, hist2, n_edges, nb);
    bucket_scan_kernel<<<1, 64, 0, stream>>>(hist2, dbase, dcursor, sbase, scursor,
                                             row_start, nb, n_nodes);
    scatter_pairs_kernel<<<sc_blocks, SC_THREADS, 0, stream>>>(
        src, dst, dcursor, scursor, pairs, sbytes, n_edges, nb);
    bucket2csr_kernel<<<nb, 256, 0, stream>>>(pairs, dbase, row_start, csr_src, n_nodes);
    count_src_kernel<<<nb, 256, 0, stream>>>(sbytes, sbase, out_deg, n_nodes);

    gemm_kernel<<<(n_nodes + BM - 1) / BM, 256, 0, stream>>>(h, W, out_deg, m, n_nodes);

    gather_kernel<<<(n_nodes + 3) / 4, 256, 0, stream>>>(row_start, csr_src, m, b, out, n_nodes);
}